// Round 8
// baseline (180.230 us; speedup 1.0000x reference)
//
#include <hip/hip_runtime.h>
#include <hip/hip_bf16.h>
#include <stdint.h>

#define M_TOK 8192
#define N_OUT 4096
#define K_IN  4096

#define BM 256
#define BN 256
#define BKB 128            // K-tile depth in BYTES (= 128 i8 elements)
#define NT (K_IN / BKB)    // 32 K-tiles

typedef __attribute__((ext_vector_type(4))) int   i32x4;
typedef __attribute__((ext_vector_type(4))) float f32x4;

#define AS1 __attribute__((address_space(1)))
#define AS3 __attribute__((address_space(3)))
#define GLOAD_LDS16(g, l) \
  __builtin_amdgcn_global_load_lds((AS1 void*)(g), (AS3 void*)(l), 16, 0, 0)

#define BAR()     __builtin_amdgcn_s_barrier()
#define WAITALL() asm volatile("s_waitcnt vmcnt(0) lgkmcnt(0)" ::: "memory")
#define VMCNT8()  asm volatile("s_waitcnt vmcnt(8)" ::: "memory")
#define LGKM12()  asm volatile("s_waitcnt lgkmcnt(12)" ::: "memory")
#define SCHEDB()  __builtin_amdgcn_sched_barrier(0)
#define PRIO(p)   __builtin_amdgcn_s_setprio(p)
#define MFMAI8(a, b, c) __builtin_amdgcn_mfma_i32_16x16x64_i8((a), (b), (c), 0, 0, 0)

// ---------------- prep: x fp32 -> i8 with per-row scale (RNE) ----------------
__global__ __launch_bounds__(256) void quant_x_i8(const float4* __restrict__ x,
                                                  int4* __restrict__ o,
                                                  float* __restrict__ scales) {
  const int row = blockIdx.x;
  const int t   = threadIdx.x;
  const float4* xr = x + (size_t)row * (K_IN / 4);
  float4 v[4];
  #pragma unroll
  for (int i = 0; i < 4; ++i) v[i] = xr[t * 4 + i];
  float m = 0.f;
  #pragma unroll
  for (int i = 0; i < 4; ++i)
    m = fmaxf(m, fmaxf(fmaxf(fabsf(v[i].x), fabsf(v[i].y)),
                       fmaxf(fabsf(v[i].z), fabsf(v[i].w))));
  #pragma unroll
  for (int off = 32; off; off >>= 1) m = fmaxf(m, __shfl_down(m, off));
  __shared__ float sm[4];
  if ((t & 63) == 0) sm[t >> 6] = m;
  __syncthreads();
  m = fmaxf(fmaxf(sm[0], sm[1]), fmaxf(sm[2], sm[3]));
  const float inv = m > 0.f ? 127.f / m : 0.f;
  if (t == 0) scales[row] = m > 0.f ? m / 127.f : 1.f;
  int q[4];
  #pragma unroll
  for (int i = 0; i < 4; ++i) {
    const int a0 = (int)rintf(v[i].x * inv);
    const int a1 = (int)rintf(v[i].y * inv);
    const int a2 = (int)rintf(v[i].z * inv);
    const int a3 = (int)rintf(v[i].w * inv);
    q[i] = (a0 & 255) | ((a1 & 255) << 8) | ((a2 & 255) << 16) | (a3 << 24);
  }
  o[(size_t)row * (K_IN / 16) + t] = make_int4(q[0], q[1], q[2], q[3]);
}

// ---------------- prep: W fp32 -> sign in i8 {-1, 0, +1} ----------------
__global__ __launch_bounds__(256) void sgn_w_i8(const float4* __restrict__ w,
                                                int4* __restrict__ o, int n16) {
  int i = blockIdx.x * blockDim.x + threadIdx.x;
  int stride = gridDim.x * blockDim.x;
  for (; i < n16; i += stride) {
    int q[4];
    #pragma unroll
    for (int j = 0; j < 4; ++j) {
      float4 v = w[i * 4 + j];
      const int a0 = v.x > 0.f ? 1 : (v.x < 0.f ? -1 : 0);
      const int a1 = v.y > 0.f ? 1 : (v.y < 0.f ? -1 : 0);
      const int a2 = v.z > 0.f ? 1 : (v.z < 0.f ? -1 : 0);
      const int a3 = v.w > 0.f ? 1 : (v.w < 0.f ? -1 : 0);
      q[j] = (a0 & 255) | ((a1 & 255) << 8) | ((a2 & 255) << 16) | (a3 << 24);
    }
    o[i] = make_int4(q[0], q[1], q[2], q[3]);
  }
}

// ======== 256x256 i8 GEMM, register-double-buffered operand pipeline ========
// C[t][o] = (x_q[t][:] . w_q[o][:]) * scale[t].  i32 accumulate (exact).
// 8 waves (2Mx4N), per-wave 128x64 out, BKB=128 B, 128 KiB LDS dbuf.
// Operand sets by k-half: setA = {a[8],b[4]}@k0, setB = @k1 (12 reads each).
// Per tile t (ONE barrier):
//   top:  issue k1(t)->setB; lgkmcnt(12) [setA retired]; sched_barrier;
//         MFMA G_k0 (32, pure-reg setA)          <- overlaps setB port drain
//   mid:  WAITALL+BAR  (buf[t] dead for all; buf[t+1] resident for all)
//   2nd:  stage(t+2)->buf[t&1]; issue k0(t+1)->setA from buf[t+1]; sched_barrier;
//         MFMA G_k1 (32, pure-reg setB)          <- overlaps setA drain + staging
// Every MFMA pure-register; read bursts (~1130 cyc port/CU) hide under 32-MFMA
// clusters (~1306 cyc matrix). lgkmcnt(12) exact by in-order DS retirement.
__global__ __launch_bounds__(512, 2) void bin_gemm_i8(const char* __restrict__ A,
                                                      const char* __restrict__ B,
                                                      const float* __restrict__ scales,
                                                      float* __restrict__ C) {
  __shared__ char lds[131072];   // 2 buf x (A 32KB + B 32KB)

  const int tid  = threadIdx.x;
  const int w    = tid >> 6;
  const int lane = tid & 63;
  const int lr   = lane & 15;    // fragment row/col
  const int lk   = lane >> 4;    // k-group 0..3 (16 bytes each)
  const int wr   = w >> 2;       // wave row 0..1  (128 rows each)
  const int wc   = w & 3;        // wave col 0..3  (64 cols each)

  const int bm = blockIdx.x >> 4;     // M/256 = 32
  const int bn = blockIdx.x & 15;     // N/256 = 16

  const char* Ag = A + (size_t)bm * BM * K_IN;
  const char* Bg = B + (size_t)bn * BN * K_IN;

  // staging: linear LDS dest + inverse-swizzled global source (rule #21).
  // chunk c (16B) of a 128-row half: row r=c>>3, source slot (c^r)&7.
  const int c0 = w * 128 + lane;
  const int c1 = c0 + 64;
  const int r0 = c0 >> 3, r1 = c1 >> 3;
  const size_t g0 = (size_t)r0 * K_IN + (size_t)(((c0 ^ r0) & 7) << 4);
  const size_t g1 = (size_t)r1 * K_IN + (size_t)(((c1 ^ r1) & 7) << 4);
  const int ldsw = w * 128 * 16;

  auto stage = [&](int mat, int half, int tt) {
    const char* g = (mat ? Bg : Ag) + (size_t)half * (128 * K_IN)
                                    + (size_t)tt * BKB;
    char* l = &lds[((tt & 1) << 16) + (mat << 15) + (half << 14) + ldsw];
    GLOAD_LDS16(g + g0, l);
    GLOAD_LDS16(g + g1, l + 1024);
  };

  // fragment reads (swizzled): (row)*128 + ((ks*64 + lk*16) ^ ((row&7)<<4));
  // row&7 == lr&7 for all fragments (16-row strides).
  const int swz   = (lr & 7) << 4;
  const int a_row = (wr * 128 + lr) * 128;
  const int b_row = 32768 + (wc * 64 + lr) * 128;
  const int k0 = (lk * 16) ^ swz;          // k bytes 0..63
  const int k1 = (64 + lk * 16) ^ swz;     // k bytes 64..127

  i32x4 acc[8][4];
  #pragma unroll
  for (int m = 0; m < 8; ++m)
    #pragma unroll
    for (int n = 0; n < 4; ++n) { i32x4 z = {0, 0, 0, 0}; acc[m][n] = z; }

  i32x4 aA[8], bA[4], aB[8], bB[4];

  // prologue: tiles 0 and 1 staged; wait tile 0; prime setA = k0(tile0)
  stage(0, 0, 0); stage(0, 1, 0); stage(1, 0, 0); stage(1, 1, 0);
  stage(0, 0, 1); stage(0, 1, 1); stage(1, 0, 1); stage(1, 1, 1);
  VMCNT8();
  BAR();
  {
    const char* L0 = &lds[0];
    #pragma unroll
    for (int m = 0; m < 8; ++m) aA[m] = *(const i32x4*)(L0 + a_row + m * 2048 + k0);
    #pragma unroll
    for (int n = 0; n < 4; ++n) bA[n] = *(const i32x4*)(L0 + b_row + n * 2048 + k0);
  }

  for (int t = 0; t < NT; ++t) {
    const char* Lc = &lds[(size_t)(t & 1) << 16];
    const char* Ln = &lds[(size_t)(~t & 1) << 16];

    // ---- top: issue k1(t) -> setB; wait setA; MFMA G_k0
    #pragma unroll
    for (int m = 0; m < 8; ++m) aB[m] = *(const i32x4*)(Lc + a_row + m * 2048 + k1);
    #pragma unroll
    for (int n = 0; n < 4; ++n) bB[n] = *(const i32x4*)(Lc + b_row + n * 2048 + k1);
    LGKM12();
    SCHEDB();
    PRIO(1);
    #pragma unroll
    for (int m = 0; m < 8; ++m)
      #pragma unroll
      for (int n = 0; n < 4; ++n)
        acc[m][n] = MFMAI8(aA[m], bA[n], acc[m][n]);
    PRIO(0);

    // ---- mid: single sync point
    WAITALL();
    BAR();

    // ---- second half: stage t+2; issue k0(t+1) -> setA; MFMA G_k1
    if (t + 2 < NT) {
      stage(1, 0, t + 2); stage(1, 1, t + 2);   // B halves
      stage(0, 0, t + 2); stage(0, 1, t + 2);   // A halves
    }
    if (t + 1 < NT) {
      #pragma unroll
      for (int m = 0; m < 8; ++m) aA[m] = *(const i32x4*)(Ln + a_row + m * 2048 + k0);
      #pragma unroll
      for (int n = 0; n < 4; ++n) bA[n] = *(const i32x4*)(Ln + b_row + n * 2048 + k0);
    }
    SCHEDB();
    PRIO(1);
    #pragma unroll
    for (int m = 0; m < 8; ++m)
      #pragma unroll
      for (int n = 0; n < 4; ++n)
        acc[m][n] = MFMAI8(aB[m], bB[n], acc[m][n]);
    PRIO(0);
  }

  // epilogue: C/D layout col=lane&15, row=(lane>>4)*4+reg; y = acc * scale[row]
  const int grow0 = bm * BM + wr * 128;
  float scl[8][4];
  #pragma unroll
  for (int m = 0; m < 8; ++m)
    #pragma unroll
    for (int j = 0; j < 4; ++j)
      scl[m][j] = scales[grow0 + m * 16 + lk * 4 + j];

  float* Cp = C + (size_t)grow0 * N_OUT + bn * BN + wc * 64;
  #pragma unroll
  for (int m = 0; m < 8; ++m)
    #pragma unroll
    for (int n = 0; n < 4; ++n)
      #pragma unroll
      for (int j = 0; j < 4; ++j)
        Cp[(size_t)(m * 16 + lk * 4 + j) * N_OUT + n * 16 + lr] =
            (float)acc[m][n][j] * scl[m][j];
}

// ---------------- fallback (ws too small): fp32 LDS-tiled, correct but slow --
__global__ __launch_bounds__(256) void fb_gemm(const float* __restrict__ x,
                                               const float* __restrict__ W,
                                               float* __restrict__ y) {
  __shared__ float xs[32][33];
  __shared__ float ws[32][33];
  const int bx = blockIdx.x;
  const int by = blockIdx.y;
  const int tx = threadIdx.x & 31;
  const int ty = threadIdx.x >> 5;
  float acc[4] = {0.f, 0.f, 0.f, 0.f};
  for (int k0 = 0; k0 < K_IN; k0 += 32) {
    #pragma unroll
    for (int i = 0; i < 4; ++i) {
      int r = ty + i * 8;
      xs[r][tx] = x[(size_t)(by * 32 + r) * K_IN + k0 + tx];
      float wv = W[(size_t)(bx * 32 + r) * K_IN + k0 + tx];
      ws[r][tx] = wv > 0.f ? 1.f : (wv < 0.f ? -1.f : 0.f);
    }
    __syncthreads();
    #pragma unroll
    for (int i = 0; i < 4; ++i) {
      int r = ty + i * 8;
      float s = acc[i];
      #pragma unroll
      for (int k = 0; k < 32; ++k) s += xs[r][k] * ws[tx][k];
      acc[i] = s;
    }
    __syncthreads();
  }
  #pragma unroll
  for (int i = 0; i < 4; ++i)
    y[(size_t)(by * 32 + ty + i * 8) * N_OUT + bx * 32 + tx] = acc[i];
}

extern "C" void kernel_launch(void* const* d_in, const int* in_sizes, int n_in,
                              void* d_out, int out_size, void* d_ws, size_t ws_size,
                              hipStream_t stream) {
  const float* x = (const float*)d_in[0];   // [8192, 4096]
  const float* W = (const float*)d_in[1];   // [4096, 4096]
  float* y = (float*)d_out;                 // [8192, 4096]

  const size_t need = (size_t)M_TOK * K_IN + (size_t)N_OUT * K_IN
                    + (size_t)M_TOK * sizeof(float);
  if (ws_size >= need) {
    char*  xq = (char*)d_ws;
    char*  wq = xq + (size_t)M_TOK * K_IN;
    float* sc = (float*)(wq + (size_t)N_OUT * K_IN);
    quant_x_i8<<<M_TOK, 256, 0, stream>>>((const float4*)x, (int4*)xq, sc);
    sgn_w_i8<<<2048, 256, 0, stream>>>((const float4*)W, (int4*)wq,
                                       N_OUT * K_IN / 16);
    bin_gemm_i8<<<(M_TOK / BM) * (N_OUT / BN), 512, 0, stream>>>(xq, wq, sc, y);
  } else {
    dim3 g(N_OUT / 32, M_TOK / 32);
    fb_gemm<<<g, 256, 0, stream>>>(x, W, y);
  }
}

// Round 9
// 178.802 us; speedup vs baseline: 1.0080x; 1.0080x over previous
//
#include <hip/hip_runtime.h>
#include <hip/hip_bf16.h>
#include <stdint.h>

#define M_TOK 8192
#define N_OUT 4096
#define K_IN  4096

#define BM 256
#define BN 256
#define BKB 128            // K-tile depth in BYTES (= 128 i8 elements)
#define NT (K_IN / BKB)    // 32 K-tiles

typedef __attribute__((ext_vector_type(4))) int   i32x4;
typedef __attribute__((ext_vector_type(4))) float f32x4;

#define AS1 __attribute__((address_space(1)))
#define AS3 __attribute__((address_space(3)))
#define GLOAD_LDS16(g, l) \
  __builtin_amdgcn_global_load_lds((AS1 void*)(g), (AS3 void*)(l), 16, 0, 0)

#define BAR()     __builtin_amdgcn_s_barrier()
#define WAITALL() asm volatile("s_waitcnt vmcnt(0) lgkmcnt(0)" ::: "memory")
#define VMCNT8()  asm volatile("s_waitcnt vmcnt(8)" ::: "memory")
#define SCHEDB()  __builtin_amdgcn_sched_barrier(0)
#define PRIO(p)   __builtin_amdgcn_s_setprio(p)
#define MFMAI8(a, b, c) __builtin_amdgcn_mfma_i32_16x16x64_i8((a), (b), (c), 0, 0, 0)

// ---------------- prep: x fp32 -> i8 with per-row scale (RNE) ----------------
__global__ __launch_bounds__(256) void quant_x_i8(const float4* __restrict__ x,
                                                  int4* __restrict__ o,
                                                  float* __restrict__ scales) {
  const int row = blockIdx.x;
  const int t   = threadIdx.x;
  const float4* xr = x + (size_t)row * (K_IN / 4);
  float4 v[4];
  #pragma unroll
  for (int i = 0; i < 4; ++i) v[i] = xr[t * 4 + i];
  float m = 0.f;
  #pragma unroll
  for (int i = 0; i < 4; ++i)
    m = fmaxf(m, fmaxf(fmaxf(fabsf(v[i].x), fabsf(v[i].y)),
                       fmaxf(fabsf(v[i].z), fabsf(v[i].w))));
  #pragma unroll
  for (int off = 32; off; off >>= 1) m = fmaxf(m, __shfl_down(m, off));
  __shared__ float sm[4];
  if ((t & 63) == 0) sm[t >> 6] = m;
  __syncthreads();
  m = fmaxf(fmaxf(sm[0], sm[1]), fmaxf(sm[2], sm[3]));
  const float inv = m > 0.f ? 127.f / m : 0.f;
  if (t == 0) scales[row] = m > 0.f ? m / 127.f : 1.f;
  int q[4];
  #pragma unroll
  for (int i = 0; i < 4; ++i) {
    const int a0 = (int)rintf(v[i].x * inv);
    const int a1 = (int)rintf(v[i].y * inv);
    const int a2 = (int)rintf(v[i].z * inv);
    const int a3 = (int)rintf(v[i].w * inv);
    q[i] = (a0 & 255) | ((a1 & 255) << 8) | ((a2 & 255) << 16) | (a3 << 24);
  }
  o[(size_t)row * (K_IN / 16) + t] = make_int4(q[0], q[1], q[2], q[3]);
}

// ---------------- prep: W fp32 -> sign in i8 {-1, 0, +1} ----------------
__global__ __launch_bounds__(256) void sgn_w_i8(const float4* __restrict__ w,
                                                int4* __restrict__ o, int n16) {
  int i = blockIdx.x * blockDim.x + threadIdx.x;
  int stride = gridDim.x * blockDim.x;
  for (; i < n16; i += stride) {
    int q[4];
    #pragma unroll
    for (int j = 0; j < 4; ++j) {
      float4 v = w[i * 4 + j];
      const int a0 = v.x > 0.f ? 1 : (v.x < 0.f ? -1 : 0);
      const int a1 = v.y > 0.f ? 1 : (v.y < 0.f ? -1 : 0);
      const int a2 = v.z > 0.f ? 1 : (v.z < 0.f ? -1 : 0);
      const int a3 = v.w > 0.f ? 1 : (v.w < 0.f ? -1 : 0);
      q[j] = (a0 & 255) | ((a1 & 255) << 8) | ((a2 & 255) << 16) | (a3 << 24);
    }
    o[i] = make_int4(q[0], q[1], q[2], q[3]);
  }
}

// ======== 256x256 i8 GEMM, fine-grained read/MFMA interleave ========
// C[t][o] = (x_q[t][:] . w_q[o][:]) * scale[t].  i32 accumulate (exact).
// 8 waves (2Mx4N), per-wave 128x64 out, BKB=128 B, 128 KiB LDS dbuf.
// Key mechanism (round-8 post-mortem): per-wave issue is IN-ORDER, and a
// bunched 12-read burst stalls at issue once the CU DS-queue fills, gating the
// MFMAs behind it for every (barrier-synced) wave -> port and matrix pipe
// serialize. Fix: emit {3 ds_reads (next k-half) | 8 MFMA (cur k-half)} x 4
// per half-tile, sched_barrier-pinned. MFMA clusters are the issue-time
// spacers during which the port drains; reads never back up the queue.
// Per tile t (ONE barrier):
//   half A: interleave [read k1(t)->setB | MFMA G_k0 from setA]
//   mid:    WAITALL+BAR (buf[t] reads retired everywhere => buf[t] dead;
//           stage(t+1) drained everywhere => buf[t+1] resident)
//   half B: stage(t+2)->buf[t&1]; interleave [read k0(t+1)->setA from buf[t+1]
//           | MFMA G_k1 from setB]
__global__ __launch_bounds__(512, 2) void bin_gemm_i8(const char* __restrict__ A,
                                                      const char* __restrict__ B,
                                                      const float* __restrict__ scales,
                                                      float* __restrict__ C) {
  __shared__ char lds[131072];   // 2 buf x (A 32KB + B 32KB)

  const int tid  = threadIdx.x;
  const int w    = tid >> 6;
  const int lane = tid & 63;
  const int lr   = lane & 15;    // fragment row/col
  const int lk   = lane >> 4;    // k-group 0..3 (16 bytes each)
  const int wr   = w >> 2;       // wave row 0..1  (128 rows each)
  const int wc   = w & 3;        // wave col 0..3  (64 cols each)

  const int bm = blockIdx.x >> 4;     // M/256 = 32
  const int bn = blockIdx.x & 15;     // N/256 = 16

  const char* Ag = A + (size_t)bm * BM * K_IN;
  const char* Bg = B + (size_t)bn * BN * K_IN;

  // staging: linear LDS dest + inverse-swizzled global source (rule #21).
  // chunk c (16B) of a 128-row half: row r=c>>3, source slot (c^r)&7.
  const int c0 = w * 128 + lane;
  const int c1 = c0 + 64;
  const int r0 = c0 >> 3, r1 = c1 >> 3;
  const size_t g0 = (size_t)r0 * K_IN + (size_t)(((c0 ^ r0) & 7) << 4);
  const size_t g1 = (size_t)r1 * K_IN + (size_t)(((c1 ^ r1) & 7) << 4);
  const int ldsw = w * 128 * 16;

  auto stage = [&](int mat, int half, int tt) {
    const char* g = (mat ? Bg : Ag) + (size_t)half * (128 * K_IN)
                                    + (size_t)tt * BKB;
    char* l = &lds[((tt & 1) << 16) + (mat << 15) + (half << 14) + ldsw];
    GLOAD_LDS16(g + g0, l);
    GLOAD_LDS16(g + g1, l + 1024);
  };

  // fragment reads (swizzled): (row)*128 + ((ks*64 + lk*16) ^ ((row&7)<<4));
  // row&7 == lr&7 for all fragments (16-row strides).
  const int swz   = (lr & 7) << 4;
  const int a_row = (wr * 128 + lr) * 128;
  const int b_row = 32768 + (wc * 64 + lr) * 128;
  const int k0 = (lk * 16) ^ swz;          // k bytes 0..63
  const int k1 = (64 + lk * 16) ^ swz;     // k bytes 64..127

  i32x4 acc[8][4];
  #pragma unroll
  for (int m = 0; m < 8; ++m)
    #pragma unroll
    for (int n = 0; n < 4; ++n) { i32x4 z = {0, 0, 0, 0}; acc[m][n] = z; }

  i32x4 aA[8], bA[4], aB[8], bB[4];

  // prologue: tiles 0 and 1 staged; wait tile 0; prime setA = k0(tile0)
  stage(0, 0, 0); stage(0, 1, 0); stage(1, 0, 0); stage(1, 1, 0);
  stage(0, 0, 1); stage(0, 1, 1); stage(1, 0, 1); stage(1, 1, 1);
  VMCNT8();
  BAR();
  {
    const char* L0 = &lds[0];
    #pragma unroll
    for (int m = 0; m < 8; ++m) aA[m] = *(const i32x4*)(L0 + a_row + m * 2048 + k0);
    #pragma unroll
    for (int n = 0; n < 4; ++n) bA[n] = *(const i32x4*)(L0 + b_row + n * 2048 + k0);
  }

  for (int t = 0; t < NT; ++t) {
    const char* Lc = &lds[(size_t)(t & 1) << 16];
    const char* Ln = &lds[(size_t)(~t & 1) << 16];

    // ---- half A: interleave {3 reads k1(t)->setB | 8 MFMA G_k0 (setA)} x 4
    PRIO(1);
    #pragma unroll
    for (int q = 0; q < 4; ++q) {
      bB[q]         = *(const i32x4*)(Lc + b_row + q * 2048 + k1);
      aB[2 * q]     = *(const i32x4*)(Lc + a_row + (2 * q) * 2048 + k1);
      aB[2 * q + 1] = *(const i32x4*)(Lc + a_row + (2 * q + 1) * 2048 + k1);
      SCHEDB();
      #pragma unroll
      for (int m = 0; m < 8; ++m)
        acc[m][q] = MFMAI8(aA[m], bA[q], acc[m][q]);
      SCHEDB();
    }
    PRIO(0);

    // ---- mid: single sync point
    WAITALL();
    BAR();

    // ---- half B: stage t+2; interleave {3 reads k0(t+1)->setA | 8 MFMA G_k1}
    if (t + 2 < NT) {
      stage(1, 0, t + 2); stage(1, 1, t + 2);   // B halves
      stage(0, 0, t + 2); stage(0, 1, t + 2);   // A halves
    }
    PRIO(1);
    #pragma unroll
    for (int q = 0; q < 4; ++q) {
      if (t + 1 < NT) {
        bA[q]         = *(const i32x4*)(Ln + b_row + q * 2048 + k0);
        aA[2 * q]     = *(const i32x4*)(Ln + a_row + (2 * q) * 2048 + k0);
        aA[2 * q + 1] = *(const i32x4*)(Ln + a_row + (2 * q + 1) * 2048 + k0);
      }
      SCHEDB();
      #pragma unroll
      for (int m = 0; m < 8; ++m)
        acc[m][q] = MFMAI8(aB[m], bB[q], acc[m][q]);
      SCHEDB();
    }
    PRIO(0);
  }

  // epilogue: C/D layout col=lane&15, row=(lane>>4)*4+reg; y = acc * scale[row]
  const int grow0 = bm * BM + wr * 128;
  float scl[8][4];
  #pragma unroll
  for (int m = 0; m < 8; ++m)
    #pragma unroll
    for (int j = 0; j < 4; ++j)
      scl[m][j] = scales[grow0 + m * 16 + lk * 4 + j];

  float* Cp = C + (size_t)grow0 * N_OUT + bn * BN + wc * 64;
  #pragma unroll
  for (int m = 0; m < 8; ++m)
    #pragma unroll
    for (int n = 0; n < 4; ++n)
      #pragma unroll
      for (int j = 0; j < 4; ++j)
        Cp[(size_t)(m * 16 + lk * 4 + j) * N_OUT + n * 16 + lr] =
            (float)acc[m][n][j] * scl[m][j];
}

// ---------------- fallback (ws too small): fp32 LDS-tiled, correct but slow --
__global__ __launch_bounds__(256) void fb_gemm(const float* __restrict__ x,
                                               const float* __restrict__ W,
                                               float* __restrict__ y) {
  __shared__ float xs[32][33];
  __shared__ float ws[32][33];
  const int bx = blockIdx.x;
  const int by = blockIdx.y;
  const int tx = threadIdx.x & 31;
  const int ty = threadIdx.x >> 5;
  float acc[4] = {0.f, 0.f, 0.f, 0.f};
  for (int k0 = 0; k0 < K_IN; k0 += 32) {
    #pragma unroll
    for (int i = 0; i < 4; ++i) {
      int r = ty + i * 8;
      xs[r][tx] = x[(size_t)(by * 32 + r) * K_IN + k0 + tx];
      float wv = W[(size_t)(bx * 32 + r) * K_IN + k0 + tx];
      ws[r][tx] = wv > 0.f ? 1.f : (wv < 0.f ? -1.f : 0.f);
    }
    __syncthreads();
    #pragma unroll
    for (int i = 0; i < 4; ++i) {
      int r = ty + i * 8;
      float s = acc[i];
      #pragma unroll
      for (int k = 0; k < 32; ++k) s += xs[r][k] * ws[tx][k];
      acc[i] = s;
    }
    __syncthreads();
  }
  #pragma unroll
  for (int i = 0; i < 4; ++i)
    y[(size_t)(by * 32 + ty + i * 8) * N_OUT + bx * 32 + tx] = acc[i];
}

extern "C" void kernel_launch(void* const* d_in, const int* in_sizes, int n_in,
                              void* d_out, int out_size, void* d_ws, size_t ws_size,
                              hipStream_t stream) {
  const float* x = (const float*)d_in[0];   // [8192, 4096]
  const float* W = (const float*)d_in[1];   // [4096, 4096]
  float* y = (float*)d_out;                 // [8192, 4096]

  const size_t need = (size_t)M_TOK * K_IN + (size_t)N_OUT * K_IN
                    + (size_t)M_TOK * sizeof(float);
  if (ws_size >= need) {
    char*  xq = (char*)d_ws;
    char*  wq = xq + (size_t)M_TOK * K_IN;
    float* sc = (float*)(wq + (size_t)N_OUT * K_IN);
    quant_x_i8<<<M_TOK, 256, 0, stream>>>((const float4*)x, (int4*)xq, sc);
    sgn_w_i8<<<2048, 256, 0, stream>>>((const float4*)W, (int4*)wq,
                                       N_OUT * K_IN / 16);
    bin_gemm_i8<<<(M_TOK / BM) * (N_OUT / BN), 512, 0, stream>>>(xq, wq, sc, y);
  } else {
    dim3 g(N_OUT / 32, M_TOK / 32);
    fb_gemm<<<g, 256, 0, stream>>>(x, W, y);
  }
}